// Round 6
// baseline (1360.853 us; speedup 1.0000x reference)
//
#include <hip/hip_runtime.h>

typedef unsigned int u32;
typedef unsigned short u16;
typedef __bf16 bf16x8 __attribute__((ext_vector_type(8)));
typedef float f32x4 __attribute__((ext_vector_type(4)));
typedef u32 u32x4 __attribute__((ext_vector_type(4)));
typedef u32 u32x2 __attribute__((ext_vector_type(2)));

#define NTOK 64
#define CDIM 256
#define NH 8

// ---- workspace layout (u16 units, after 16-byte flag header) ----
#define WS_HDR 8
#define BIAS_O (WS_HDR)             // [8][n 64][m 64] expanded bias (32768)
#define WQKV_O (BIAS_O + 32768)     // w_qkv bf16                    (196608)
#define BQKV_O (WQKV_O + 196608)    // b_qkv bf16                    (768)
#define WPRJ_O (BQKV_O + 768)       // w_proj bf16                   (65536)
#define BPRJ_O (WPRJ_O + 65536)     // b_proj bf16                   (256)

// ---- LDS: 66,560 B -> 2 blocks/CU ----
// QS [64][520B] q  (wave w writes/reads only cols 32w..32w+32)
// KS [64][520B] k  (same ownership)
// P_h (8KB, h*8192) overlays QS+KS after the post-QK barrier
// y  [64][520B] overlays bytes 0..33280 after the post-PV barrier
#define XROW 520
#define QS_OFF 0
#define KS_OFF 33280
#define LDS_BYTES 66560

__device__ __forceinline__ float bf2f(u16 u) {
  union { u32 i; float f; } z; z.i = ((u32)u) << 16; return z.f;
}
__device__ __forceinline__ u16 f2bf(float f) {
  __bf16 h = (__bf16)f; return __builtin_bit_cast(u16, h);
}
__device__ __forceinline__ float fetchf(const void* p, int idx, int isbf) {
  return isbf ? bf2f(((const u16*)p)[idx]) : ((const float*)p)[idx];
}

__global__ void detect_dtype(const u16* __restrict__ x, int* __restrict__ flag) {
  __shared__ int cnt;
  if (threadIdx.x == 0) cnt = 0;
  __syncthreads();
  int sane = 0;
  for (int i = threadIdx.x; i < 2048; i += 256) {
    u16 u = x[2 * i];
    int e = (u >> 7) & 0xFF;
    sane += (e == 0 || (e >= 90 && e <= 160)) ? 1 : 0;
  }
  atomicAdd(&cnt, sane);
  __syncthreads();
  if (threadIdx.x == 0) *flag = (cnt >= 1638) ? 1 : 0;
}

// bias expanded to [h][n][m] (n-major: S^T lane holds 4 consecutive m -> one 8B read)
__global__ void cvt_params(const void* __restrict__ wqkv, const void* __restrict__ bqkv,
                           const void* __restrict__ btab, const void* __restrict__ wprj,
                           const void* __restrict__ bprj, void* __restrict__ wsraw) {
  u16* ws = (u16*)wsraw;
  const int isbf = *(const int*)wsraw;
  int i = blockIdx.x * 256 + threadIdx.x;
  if (i < 32768) {
    int n = (i >> 6) & 63, m = i & 63, h = i >> 12;
    int r0 = (n >> 3) - (m >> 3) + 7, r1 = (n & 7) - (m & 7) + 7;
    ws[BIAS_O + i] = f2bf(fetchf(btab, (r0 * 15 + r1) * NH + h, isbf));
  } else if (i < 32768 + 196608) {
    int j = i - 32768;
    ws[WQKV_O + j] = f2bf(fetchf(wqkv, j, isbf));
  } else if (i < 32768 + 196608 + 768) {
    int j = i - (32768 + 196608);
    ws[BQKV_O + j] = f2bf(fetchf(bqkv, j, isbf));
  } else if (i < 32768 + 196608 + 768 + 65536) {
    int j = i - (32768 + 196608 + 768);
    ws[WPRJ_O + j] = f2bf(fetchf(wprj, j, isbf));
  } else if (i < 32768 + 196608 + 768 + 65536 + 256) {
    int j = i - (32768 + 196608 + 768 + 65536);
    ws[BPRJ_O + j] = f2bf(fetchf(bprj, j, isbf));
  }
}

__global__ __launch_bounds__(512, 4)
void win_attn_fused(const void* __restrict__ xraw, const void* __restrict__ wsraw,
                    float* __restrict__ out)
{
  __shared__ __align__(16) unsigned char lds[LDS_BYTES];
  const u16* ws  = (const u16*)wsraw;
  const int isbf = *(const int*)wsraw;
  const int b    = blockIdx.x;
  const int tid  = threadIdx.x;
  const int w    = tid >> 6;     // wave id = head id
  const int lane = tid & 63;
  const int c    = lane & 15;
  const int g    = lane >> 4;
  const float scale = 0.1767766952966369f;  // 32^-0.5

  u32 vpk[2][4][2];   // v of head w, bf16-packed: [dhalf jt][row-tile rt][token pair]

  // ---- stage 1: qkv cols 32w..32w+32 of q,k,v. x frags direct from global,
  //      two row-halves to bound VGPR (af[2][8] = 64 regs live).
  {
    const u16*   x16 = (const u16*)xraw + (size_t)b * (NTOK * CDIM);
    const float* xf  = (const float*)xraw + (size_t)b * (NTOK * CDIM);
#pragma unroll
    for (int half = 0; half < 2; ++half) {
      bf16x8 af[2][8];
#pragma unroll
      for (int rt2 = 0; rt2 < 2; ++rt2)
#pragma unroll
        for (int ks = 0; ks < 8; ++ks) {
          const int off = (32 * half + 16 * rt2 + c) * CDIM + ks * 32 + g * 8;
          if (isbf) {
            af[rt2][ks] = *(const bf16x8*)(x16 + off);
          } else {
            f32x4 lo = *(const f32x4*)(xf + off);
            f32x4 hi = *(const f32x4*)(xf + off + 4);
            u32x4 pk;
            pk[0] = (u32)f2bf(lo[0]) | ((u32)f2bf(lo[1]) << 16);
            pk[1] = (u32)f2bf(lo[2]) | ((u32)f2bf(lo[3]) << 16);
            pk[2] = (u32)f2bf(hi[0]) | ((u32)f2bf(hi[1]) << 16);
            pk[3] = (u32)f2bf(hi[2]) | ((u32)f2bf(hi[3]) << 16);
            af[rt2][ks] = __builtin_bit_cast(bf16x8, pk);
          }
        }
#pragma unroll
      for (int t = 0; t < 3; ++t)          // q, k, v
#pragma unroll
        for (int jt = 0; jt < 2; ++jt) {
          const int lcol = w * 32 + jt * 16 + c;   // 0..255
          const int colw = t * 256 + lcol;
          f32x4 acc[2] = {{0,0,0,0},{0,0,0,0}};
          const u16* wrow = ws + WQKV_O + colw * CDIM;
#pragma unroll
          for (int ks = 0; ks < 8; ++ks) {
            bf16x8 bf = *(const bf16x8*)(wrow + ks * 32 + g * 8);
            acc[0] = __builtin_amdgcn_mfma_f32_16x16x32_bf16(af[0][ks], bf, acc[0], 0, 0, 0);
            acc[1] = __builtin_amdgcn_mfma_f32_16x16x32_bf16(af[1][ks], bf, acc[1], 0, 0, 0);
          }
          const float badd = bf2f(ws[BQKV_O + colw]);
#pragma unroll
          for (int rt2 = 0; rt2 < 2; ++rt2) {
            if (t == 0) {
#pragma unroll
              for (int reg = 0; reg < 4; ++reg) {
                int r = 32 * half + 16 * rt2 + 4 * g + reg;
                *(u16*)(lds + QS_OFF + r * XROW + lcol * 2) = f2bf((acc[rt2][reg] + badd) * scale);
              }
            } else if (t == 1) {
#pragma unroll
              for (int reg = 0; reg < 4; ++reg) {
                int r = 32 * half + 16 * rt2 + 4 * g + reg;
                *(u16*)(lds + KS_OFF + r * XROW + lcol * 2) = f2bf(acc[rt2][reg] + badd);
              }
            } else {   // v -> registers (bf16 pairs of consecutive tokens)
              vpk[jt][2 * half + rt2][0] =
                  (u32)f2bf(acc[rt2][0] + badd) | ((u32)f2bf(acc[rt2][1] + badd) << 16);
              vpk[jt][2 * half + rt2][1] =
                  (u32)f2bf(acc[rt2][2] + badd) | ((u32)f2bf(acc[rt2][3] + badd) << 16);
            }
          }
        }
    }
  }
  asm volatile("" ::: "memory");   // u16 q/k stores -> bf16x8 reads (same wave, in-order LDS)

  // ---- stage 2a fragments (own head's cols only -> no barrier needed)
  bf16x8 bk[4], aq[4];
#pragma unroll
  for (int rt = 0; rt < 4; ++rt)
    bk[rt] = *(const bf16x8*)(lds + KS_OFF + (16 * rt + c) * XROW + w * 64 + g * 16);
#pragma unroll
  for (int ct = 0; ct < 4; ++ct)
    aq[ct] = *(const bf16x8*)(lds + QS_OFF + (16 * ct + c) * XROW + w * 64 + g * 16);
  __syncthreads();   // B1: all q/k reads in regs -> q/k LDS free for P overlay

  // ---- S^T = k·q^T + bias^T : lane (c,g) holds S^T[m=16rt+4g+reg][n=16ct+c]
  f32x4 sT[4][4];
#pragma unroll
  for (int rt = 0; rt < 4; ++rt)
#pragma unroll
    for (int ct = 0; ct < 4; ++ct) {
      u32x2 bp = *(const u32x2*)(ws + BIAS_O + (w << 12) + ((16 * ct + c) << 6) + 16 * rt + 4 * g);
      sT[rt][ct][0] = bf2f((u16)(bp[0] & 0xffff));
      sT[rt][ct][1] = bf2f((u16)(bp[0] >> 16));
      sT[rt][ct][2] = bf2f((u16)(bp[1] & 0xffff));
      sT[rt][ct][3] = bf2f((u16)(bp[1] >> 16));
    }
#pragma unroll
  for (int rt = 0; rt < 4; ++rt)
#pragma unroll
    for (int ct = 0; ct < 4; ++ct)
      sT[rt][ct] = __builtin_amdgcn_mfma_f32_16x16x32_bf16(bk[rt], aq[ct], sT[rt][ct], 0, 0, 0);

  // ---- softmax over m (per n-col ct): 16 local + 2 shfl_xor across g-groups
#pragma unroll
  for (int ct = 0; ct < 4; ++ct) {
    float mx = sT[0][ct][0];
#pragma unroll
    for (int rt = 0; rt < 4; ++rt)
#pragma unroll
      for (int reg = 0; reg < 4; ++reg) mx = fmaxf(mx, sT[rt][ct][reg]);
    mx = fmaxf(mx, __shfl_xor(mx, 16));
    mx = fmaxf(mx, __shfl_xor(mx, 32));
    float sum = 0.f;
#pragma unroll
    for (int rt = 0; rt < 4; ++rt)
#pragma unroll
      for (int reg = 0; reg < 4; ++reg) {
        float e = __expf(sT[rt][ct][reg] - mx);
        sT[rt][ct][reg] = e; sum += e;
      }
    sum += __shfl_xor(sum, 16);
    sum += __shfl_xor(sum, 32);
    float inv = 1.0f / sum;
#pragma unroll
    for (int rt = 0; rt < 4; ++rt)
#pragma unroll
      for (int reg = 0; reg < 4; ++reg) sT[rt][ct][reg] *= inv;
  }

  // ---- P -> own 8KB slab (overlays q/k, own-wave only): 16x ds_write_b64, swizzled
  const int Pb = w * 8192;
#pragma unroll
  for (int rt = 0; rt < 4; ++rt)
#pragma unroll
    for (int ct = 0; ct < 4; ++ct) {
      int n = 16 * ct + c;
      int byte = (n * 128 + 32 * rt + 8 * g) ^ ((n & 7) << 4);
      u32x2 pk;
      pk[0] = (u32)f2bf(sT[rt][ct][0]) | ((u32)f2bf(sT[rt][ct][1]) << 16);
      pk[1] = (u32)f2bf(sT[rt][ct][2]) | ((u32)f2bf(sT[rt][ct][3]) << 16);
      *(u32x2*)(lds + Pb + byte) = pk;
    }
  asm volatile("" ::: "memory");

  // ---- v repack: acc layout v[16rt+4g'+reg][d=16ct2+c] -> B-frag vT[d=16ct2+c][t=32ks+8g+j]
  // j<4 from lane (c, g'=2g mod 4) = c+32*(g&1); j>=4 from +16; rt' = 2ks+(g>>1).
  bf16x8 bv[2][2];
#pragma unroll
  for (int ct2 = 0; ct2 < 2; ++ct2)
#pragma unroll
    for (int ks = 0; ks < 2; ++ks) {
      const int s0 = c + 32 * (g & 1), s1 = s0 + 16;
      u32 A0 = (u32)__shfl((int)vpk[ct2][2 * ks    ][0], s0, 64);
      u32 A1 = (u32)__shfl((int)vpk[ct2][2 * ks    ][1], s0, 64);
      u32 B0 = (u32)__shfl((int)vpk[ct2][2 * ks + 1][0], s0, 64);
      u32 B1 = (u32)__shfl((int)vpk[ct2][2 * ks + 1][1], s0, 64);
      u32 C0 = (u32)__shfl((int)vpk[ct2][2 * ks    ][0], s1, 64);
      u32 C1 = (u32)__shfl((int)vpk[ct2][2 * ks    ][1], s1, 64);
      u32 D0 = (u32)__shfl((int)vpk[ct2][2 * ks + 1][0], s1, 64);
      u32 D1 = (u32)__shfl((int)vpk[ct2][2 * ks + 1][1], s1, 64);
      const bool hi = (g >> 1) & 1;
      u32x4 f;
      f[0] = hi ? B0 : A0;  f[1] = hi ? B1 : A1;
      f[2] = hi ? D0 : C0;  f[3] = hi ? D1 : C1;
      bv[ct2][ks] = __builtin_bit_cast(bf16x8, f);
    }

  // ---- PV: y[n][d] ; A = P rows (m-contig), B = vT rows (token-contig)
  f32x4 o[4][2] = {{{0,0,0,0},{0,0,0,0}},{{0,0,0,0},{0,0,0,0}},
                   {{0,0,0,0},{0,0,0,0}},{{0,0,0,0},{0,0,0,0}}};
#pragma unroll
  for (int ks = 0; ks < 2; ++ks)
#pragma unroll
    for (int rt = 0; rt < 4; ++rt) {
      int n = 16 * rt + c;
      bf16x8 pa = *(const bf16x8*)(lds + Pb + ((n * 128 + 64 * ks + 16 * g) ^ ((n & 7) << 4)));
      o[rt][0] = __builtin_amdgcn_mfma_f32_16x16x32_bf16(pa, bv[0][ks], o[rt][0], 0, 0, 0);
      o[rt][1] = __builtin_amdgcn_mfma_f32_16x16x32_bf16(pa, bv[1][ks], o[rt][1], 0, 0, 0);
    }
  __syncthreads();   // B2: all P reads done -> y may overlay bytes 0..33280

  // ---- y[n][32w+16ct2+c] -> LDS rows [64][520]
#pragma unroll
  for (int rt = 0; rt < 4; ++rt)
#pragma unroll
    for (int ct2 = 0; ct2 < 2; ++ct2)
#pragma unroll
      for (int reg = 0; reg < 4; ++reg) {
        int n = 16 * rt + 4 * g + reg;
        int col = w * 32 + 16 * ct2 + c;
        *(u16*)(lds + n * XROW + col * 2) = f2bf(o[rt][ct2][reg]);
      }
  __syncthreads();   // B3: y complete

  // ---- stage 4: out = y @ w_proj^T + b_proj ; direct f32 scatter (64B segments)
  float* gout = out + (size_t)b * (NTOK * CDIM);
  {
    bf16x8 ay[4][8];
#pragma unroll
    for (int rt = 0; rt < 4; ++rt)
#pragma unroll
      for (int ks = 0; ks < 8; ++ks)
        ay[rt][ks] = *(const bf16x8*)(lds + (16 * rt + c) * XROW + ks * 64 + g * 16);
#pragma unroll
    for (int ct = 0; ct < 2; ++ct) {
      const int colw = w * 32 + ct * 16 + c;
      const float badd = bf2f(ws[BPRJ_O + colw]);
      f32x4 acc[4];
#pragma unroll
      for (int rt = 0; rt < 4; ++rt)
#pragma unroll
        for (int reg = 0; reg < 4; ++reg) acc[rt][reg] = badd;
      const u16* wrow = ws + WPRJ_O + colw * CDIM;
#pragma unroll
      for (int ks = 0; ks < 8; ++ks) {
        bf16x8 bf = *(const bf16x8*)(wrow + ks * 32 + g * 8);
#pragma unroll
        for (int rt = 0; rt < 4; ++rt)
          acc[rt] = __builtin_amdgcn_mfma_f32_16x16x32_bf16(ay[rt][ks], bf, acc[rt], 0, 0, 0);
      }
#pragma unroll
      for (int rt = 0; rt < 4; ++rt)
#pragma unroll
        for (int reg = 0; reg < 4; ++reg) {
          int n = 16 * rt + 4 * g + reg;
          gout[n * CDIM + colw] = acc[rt][reg];
        }
    }
  }
}

extern "C" void kernel_launch(void* const* d_in, const int* in_sizes, int n_in,
                              void* d_out, int out_size, void* d_ws, size_t ws_size,
                              hipStream_t stream) {
  (void)in_sizes; (void)n_in; (void)out_size; (void)ws_size;
  detect_dtype<<<dim3(1), dim3(256), 0, stream>>>((const u16*)d_in[0], (int*)d_ws);
  cvt_params<<<dim3(1156), dim3(256), 0, stream>>>(d_in[1], d_in[2], d_in[3], d_in[4],
                                                   d_in[5], d_ws);
  win_attn_fused<<<dim3(4096), dim3(512), 0, stream>>>(d_in[0], d_ws, (float*)d_out);
}

// Round 7
// 661.615 us; speedup vs baseline: 2.0569x; 2.0569x over previous
//
#include <hip/hip_runtime.h>

typedef unsigned int u32;
typedef unsigned short u16;
typedef __bf16 bf16x8 __attribute__((ext_vector_type(8)));
typedef float f32x4 __attribute__((ext_vector_type(4)));
typedef u32 u32x4 __attribute__((ext_vector_type(4)));
typedef u32 u32x2 __attribute__((ext_vector_type(2)));

#define NTOK 64
#define CDIM 256
#define NH 8

// ---- workspace layout (u16 units, after 16-byte flag header) ----
#define WS_HDR 8
#define BIAS_O (WS_HDR)             // [8][n 64][m 64] expanded bias (32768)
#define WQKV_O (BIAS_O + 32768)     // w_qkv bf16                    (196608)
#define BQKV_O (WQKV_O + 196608)    // b_qkv bf16                    (768)
#define WPRJ_O (BQKV_O + 768)       // w_proj bf16                   (65536)
#define BPRJ_O (WPRJ_O + 65536)     // b_proj bf16                   (256)

// ---- LDS: x tile [64][520B] = 33,280 B; reused as y tile after stage 1 ----
#define XROW 520
#define LDS_BYTES 33280

__device__ __forceinline__ float bf2f(u16 u) {
  union { u32 i; float f; } z; z.i = ((u32)u) << 16; return z.f;
}
__device__ __forceinline__ u16 f2bf(float f) {
  __bf16 h = (__bf16)f; return __builtin_bit_cast(u16, h);
}
__device__ __forceinline__ u32 pk2(float a, float b) {
  return (u32)f2bf(a) | ((u32)f2bf(b) << 16);
}
__device__ __forceinline__ float fetchf(const void* p, int idx, int isbf) {
  return isbf ? bf2f(((const u16*)p)[idx]) : ((const float*)p)[idx];
}

// Universal acc->frag repack (HW-verified form, round 6 v-repack):
// target lane (c,g) gathers 2 packed u32 from lane s0=c+32*(g&1) and 2 from s1=s0+16,
// choosing between the lo/hi source variant (P0*/P1*) by hi=(g>>1)&1.
__device__ __forceinline__ bf16x8 frag_from(u32 p00, u32 p01, u32 p10, u32 p11,
                                            int s0, int s1, bool hi) {
  u32 A0 = (u32)__shfl((int)p00, s0, 64);
  u32 A1 = (u32)__shfl((int)p01, s0, 64);
  u32 B0 = (u32)__shfl((int)p10, s0, 64);
  u32 B1 = (u32)__shfl((int)p11, s0, 64);
  u32 C0 = (u32)__shfl((int)p00, s1, 64);
  u32 C1 = (u32)__shfl((int)p01, s1, 64);
  u32 D0 = (u32)__shfl((int)p10, s1, 64);
  u32 D1 = (u32)__shfl((int)p11, s1, 64);
  u32x4 f;
  f[0] = hi ? B0 : A0;  f[1] = hi ? B1 : A1;
  f[2] = hi ? D0 : C0;  f[3] = hi ? D1 : C1;
  return __builtin_bit_cast(bf16x8, f);
}

__global__ void detect_dtype(const u16* __restrict__ x, int* __restrict__ flag) {
  __shared__ int cnt;
  if (threadIdx.x == 0) cnt = 0;
  __syncthreads();
  int sane = 0;
  for (int i = threadIdx.x; i < 2048; i += 256) {
    u16 u = x[2 * i];
    int e = (u >> 7) & 0xFF;
    sane += (e == 0 || (e >= 90 && e <= 160)) ? 1 : 0;
  }
  atomicAdd(&cnt, sane);
  __syncthreads();
  if (threadIdx.x == 0) *flag = (cnt >= 1638) ? 1 : 0;
}

// bias expanded to [h][n][m]
__global__ void cvt_params(const void* __restrict__ wqkv, const void* __restrict__ bqkv,
                           const void* __restrict__ btab, const void* __restrict__ wprj,
                           const void* __restrict__ bprj, void* __restrict__ wsraw) {
  u16* ws = (u16*)wsraw;
  const int isbf = *(const int*)wsraw;
  int i = blockIdx.x * 256 + threadIdx.x;
  if (i < 32768) {
    int n = (i >> 6) & 63, m = i & 63, h = i >> 12;
    int r0 = (n >> 3) - (m >> 3) + 7, r1 = (n & 7) - (m & 7) + 7;
    ws[BIAS_O + i] = f2bf(fetchf(btab, (r0 * 15 + r1) * NH + h, isbf));
  } else if (i < 32768 + 196608) {
    int j = i - 32768;
    ws[WQKV_O + j] = f2bf(fetchf(wqkv, j, isbf));
  } else if (i < 32768 + 196608 + 768) {
    int j = i - (32768 + 196608);
    ws[BQKV_O + j] = f2bf(fetchf(bqkv, j, isbf));
  } else if (i < 32768 + 196608 + 768 + 65536) {
    int j = i - (32768 + 196608 + 768);
    ws[WPRJ_O + j] = f2bf(fetchf(wprj, j, isbf));
  } else if (i < 32768 + 196608 + 768 + 65536 + 256) {
    int j = i - (32768 + 196608 + 768 + 65536);
    ws[BPRJ_O + j] = f2bf(fetchf(bprj, j, isbf));
  }
}

// Transposed qkv ch-tile: acc rows = channels CHB+4g+reg, cols = tokens 16nt+c.
#define TILE_T(PK, CHT, CHB, SCL) {                                                   \
    bf16x8 wf[8];                                                                     \
    const u16* wrow = ws + WQKV_O + ((CHB) + c) * CDIM;                               \
    _Pragma("unroll")                                                                 \
    for (int ks = 0; ks < 8; ++ks) wf[ks] = *(const bf16x8*)(wrow + ks * 32 + g * 8); \
    f32x4 binit;                                                                      \
    { u32x2 bp = *(const u32x2*)(ws + BQKV_O + (CHB) + 4 * g);                        \
      binit[0] = bf2f((u16)(bp[0] & 0xffff)); binit[1] = bf2f((u16)(bp[0] >> 16));    \
      binit[2] = bf2f((u16)(bp[1] & 0xffff)); binit[3] = bf2f((u16)(bp[1] >> 16)); }  \
    _Pragma("unroll")                                                                 \
    for (int nt = 0; nt < 4; ++nt) {                                                  \
      f32x4 acc = binit;                                                              \
      _Pragma("unroll")                                                               \
      for (int ks = 0; ks < 8; ++ks) {                                                \
        bf16x8 xf = *(const bf16x8*)(lds + (16 * nt + c) * XROW + ks * 64 + g * 16);  \
        acc = __builtin_amdgcn_mfma_f32_16x16x32_bf16(wf[ks], xf, acc, 0, 0, 0);      \
      }                                                                               \
      PK[CHT][nt][0] = pk2(acc[0] * (SCL), acc[1] * (SCL));                           \
      PK[CHT][nt][1] = pk2(acc[2] * (SCL), acc[3] * (SCL));                           \
    } }

// Normal qkv ch-tile (v): acc rows = tokens 16nt+4g+reg, col = channel CHB+c.
#define TILE_N(PK, CHT, CHB) {                                                        \
    bf16x8 wf[8];                                                                     \
    const u16* wrow = ws + WQKV_O + ((CHB) + c) * CDIM;                               \
    _Pragma("unroll")                                                                 \
    for (int ks = 0; ks < 8; ++ks) wf[ks] = *(const bf16x8*)(wrow + ks * 32 + g * 8); \
    const float badd = bf2f(ws[BQKV_O + (CHB) + c]);                                  \
    _Pragma("unroll")                                                                 \
    for (int nt = 0; nt < 4; ++nt) {                                                  \
      f32x4 acc = {badd, badd, badd, badd};                                           \
      _Pragma("unroll")                                                               \
      for (int ks = 0; ks < 8; ++ks) {                                                \
        bf16x8 xf = *(const bf16x8*)(lds + (16 * nt + c) * XROW + ks * 64 + g * 16);  \
        acc = __builtin_amdgcn_mfma_f32_16x16x32_bf16(xf, wf[ks], acc, 0, 0, 0);      \
      }                                                                               \
      PK[CHT][nt][0] = pk2(acc[0], acc[1]);                                           \
      PK[CHT][nt][1] = pk2(acc[2], acc[3]);                                           \
    } }

__global__ __launch_bounds__(512, 4)
void win_attn_fused(const void* __restrict__ xraw, const void* __restrict__ wsraw,
                    float* __restrict__ out)
{
  __shared__ __align__(16) unsigned char lds[LDS_BYTES];
  const u16* ws  = (const u16*)wsraw;
  const int isbf = *(const int*)wsraw;
  const int b    = blockIdx.x;
  const int tid  = threadIdx.x;
  const int w    = tid >> 6;     // wave id = head id
  const int lane = tid & 63;
  const int c    = lane & 15;
  const int g    = lane >> 4;
  const float scale = 0.1767766952966369f;  // 32^-0.5

  // ---- stage 0: x[b] (64x256) -> LDS bf16 [64][520B]
  if (isbf) {
    const u32x4* gx = (const u32x4*)((const u16*)xraw + (size_t)b * (NTOK * CDIM));
#pragma unroll
    for (int i = 0; i < 4; ++i) {
      int q = tid + i * 512;
      int row = q >> 5, c8 = q & 31;
      *(u32x4*)(lds + row * XROW + c8 * 16) = gx[q];
    }
  } else {
    const f32x4* gx = (const f32x4*)((const float*)xraw + (size_t)b * (NTOK * CDIM));
#pragma unroll
    for (int i = 0; i < 8; ++i) {
      int q = tid + i * 512;
      int row = q >> 6, c4 = q & 63;
      f32x4 v = gx[q];
      u32x2 pkv;
      pkv[0] = pk2(v[0], v[1]);
      pkv[1] = pk2(v[2], v[3]);
      *(u32x2*)(lds + row * XROW + c4 * 8) = pkv;
    }
  }
  __syncthreads();   // B1

  // ---- stage 1: per-head q,k (transposed) and v (normal), packed in registers
  u32 qpk[2][4][2], kpk[2][4][2], vpk[2][4][2];
  TILE_T(qpk, 0, 32 * w,            scale);
  TILE_T(qpk, 1, 32 * w + 16,       scale);
  TILE_T(kpk, 0, 256 + 32 * w,      1.0f);
  TILE_T(kpk, 1, 256 + 32 * w + 16, 1.0f);
  TILE_N(vpk, 0, 512 + 32 * w);
  TILE_N(vpk, 1, 512 + 32 * w + 16);
  __syncthreads();   // B2: x-LDS dead; region will hold y later

  const int s0 = c + 32 * (g & 1), s1 = s0 + 16;
  const bool hi = ((g >> 1) & 1) != 0;
  const int h = w;

  // ---- S^T = k q^T + bias^T, softmax over m, P packed in regs (per-nt strips)
  bf16x8 bkf[4];
#pragma unroll
  for (int mt = 0; mt < 4; ++mt)
    bkf[mt] = frag_from(kpk[0][mt][0], kpk[0][mt][1], kpk[1][mt][0], kpk[1][mt][1], s0, s1, hi);

  u32 Ppk[4][4][2];
#pragma unroll
  for (int nt = 0; nt < 4; ++nt) {
    bf16x8 aqf = frag_from(qpk[0][nt][0], qpk[0][nt][1], qpk[1][nt][0], qpk[1][nt][1], s0, s1, hi);
    f32x4 st[4];
#pragma unroll
    for (int mt = 0; mt < 4; ++mt) {
      u32x2 bp = *(const u32x2*)(ws + BIAS_O + (h << 12) + ((16 * nt + c) << 6) + 16 * mt + 4 * g);
      st[mt][0] = bf2f((u16)(bp[0] & 0xffff)); st[mt][1] = bf2f((u16)(bp[0] >> 16));
      st[mt][2] = bf2f((u16)(bp[1] & 0xffff)); st[mt][3] = bf2f((u16)(bp[1] >> 16));
    }
#pragma unroll
    for (int mt = 0; mt < 4; ++mt)
      st[mt] = __builtin_amdgcn_mfma_f32_16x16x32_bf16(bkf[mt], aqf, st[mt], 0, 0, 0);
    float mx = st[0][0];
#pragma unroll
    for (int mt = 0; mt < 4; ++mt)
#pragma unroll
      for (int r = 0; r < 4; ++r) mx = fmaxf(mx, st[mt][r]);
    mx = fmaxf(mx, __shfl_xor(mx, 16));
    mx = fmaxf(mx, __shfl_xor(mx, 32));
    float sum = 0.f;
#pragma unroll
    for (int mt = 0; mt < 4; ++mt)
#pragma unroll
      for (int r = 0; r < 4; ++r) { float e = __expf(st[mt][r] - mx); st[mt][r] = e; sum += e; }
    sum += __shfl_xor(sum, 16);
    sum += __shfl_xor(sum, 32);
    float inv = 1.0f / sum;
#pragma unroll
    for (int mt = 0; mt < 4; ++mt) {
      Ppk[mt][nt][0] = pk2(st[mt][0] * inv, st[mt][1] * inv);
      Ppk[mt][nt][1] = pk2(st[mt][2] * inv, st[mt][3] * inv);
    }
  }

  // ---- PV entirely in registers: pa (from Ppk), bv (from vpk), 16 mfma
  bf16x8 paf[4][2];
#pragma unroll
  for (int nt = 0; nt < 4; ++nt)
#pragma unroll
    for (int k2 = 0; k2 < 2; ++k2)
      paf[nt][k2] = frag_from(Ppk[2 * k2][nt][0], Ppk[2 * k2][nt][1],
                              Ppk[2 * k2 + 1][nt][0], Ppk[2 * k2 + 1][nt][1], s0, s1, hi);
  bf16x8 bvf[2][2];
#pragma unroll
  for (int dt = 0; dt < 2; ++dt)
#pragma unroll
    for (int k2 = 0; k2 < 2; ++k2)
      bvf[dt][k2] = frag_from(vpk[dt][2 * k2][0], vpk[dt][2 * k2][1],
                              vpk[dt][2 * k2 + 1][0], vpk[dt][2 * k2 + 1][1], s0, s1, hi);
  f32x4 o[4][2] = {{{0,0,0,0},{0,0,0,0}},{{0,0,0,0},{0,0,0,0}},
                   {{0,0,0,0},{0,0,0,0}},{{0,0,0,0},{0,0,0,0}}};
#pragma unroll
  for (int k2 = 0; k2 < 2; ++k2)
#pragma unroll
    for (int nt = 0; nt < 4; ++nt) {
      o[nt][0] = __builtin_amdgcn_mfma_f32_16x16x32_bf16(paf[nt][k2], bvf[0][k2], o[nt][0], 0, 0, 0);
      o[nt][1] = __builtin_amdgcn_mfma_f32_16x16x32_bf16(paf[nt][k2], bvf[1][k2], o[nt][1], 0, 0, 0);
    }

  // ---- y[token][32w+16dt+c] -> LDS (region freed at B2; disjoint per-wave cols)
#pragma unroll
  for (int nt = 0; nt < 4; ++nt)
#pragma unroll
    for (int dt = 0; dt < 2; ++dt)
#pragma unroll
      for (int r = 0; r < 4; ++r) {
        int n = 16 * nt + 4 * g + r, col = 32 * w + 16 * dt + c;
        *(u16*)(lds + n * XROW + col * 2) = f2bf(o[nt][dt][r]);
      }
  __syncthreads();   // B3: y complete

  // ---- proj: out = y @ w_proj^T + b_proj ; direct f32 scatter (64B segments)
  float* gout = out + (size_t)b * (NTOK * CDIM);
#pragma unroll
  for (int ct = 0; ct < 2; ++ct) {
    const int colw = 32 * w + 16 * ct + c;
    const float badd = bf2f(ws[BPRJ_O + colw]);
    f32x4 acc[4];
#pragma unroll
    for (int rt = 0; rt < 4; ++rt)
#pragma unroll
      for (int r = 0; r < 4; ++r) acc[rt][r] = badd;
    const u16* wrow = ws + WPRJ_O + colw * CDIM;
#pragma unroll
    for (int ks = 0; ks < 8; ++ks) {
      bf16x8 wf = *(const bf16x8*)(wrow + ks * 32 + g * 8);
#pragma unroll
      for (int rt = 0; rt < 4; ++rt) {
        bf16x8 ay = *(const bf16x8*)(lds + (16 * rt + c) * XROW + ks * 64 + g * 16);
        acc[rt] = __builtin_amdgcn_mfma_f32_16x16x32_bf16(ay, wf, acc[rt], 0, 0, 0);
      }
    }
#pragma unroll
    for (int rt = 0; rt < 4; ++rt)
#pragma unroll
      for (int r = 0; r < 4; ++r) {
        int n = 16 * rt + 4 * g + r;
        gout[n * CDIM + colw] = acc[rt][r];
      }
  }
}

extern "C" void kernel_launch(void* const* d_in, const int* in_sizes, int n_in,
                              void* d_out, int out_size, void* d_ws, size_t ws_size,
                              hipStream_t stream) {
  (void)in_sizes; (void)n_in; (void)out_size; (void)ws_size;
  detect_dtype<<<dim3(1), dim3(256), 0, stream>>>((const u16*)d_in[0], (int*)d_ws);
  cvt_params<<<dim3(1156), dim3(256), 0, stream>>>(d_in[1], d_in[2], d_in[3], d_in[4],
                                                   d_in[5], d_ws);
  win_attn_fused<<<dim3(4096), dim3(512), 0, stream>>>(d_in[0], d_ws, (float*)d_out);
}

// Round 8
// 466.615 us; speedup vs baseline: 2.9164x; 1.4179x over previous
//
#include <hip/hip_runtime.h>

typedef unsigned int u32;
typedef unsigned short u16;
typedef __bf16 bf16x8 __attribute__((ext_vector_type(8)));
typedef float f32x4 __attribute__((ext_vector_type(4)));
typedef u32 u32x4 __attribute__((ext_vector_type(4)));
typedef u32 u32x2 __attribute__((ext_vector_type(2)));

#define NTOK 64
#define CDIM 256
#define NH 8

// ---- workspace layout (u16 units, after 16-byte flag header) ----
#define WS_HDR 8
#define BIAS_O (WS_HDR)             // [8][n 64][m 64] expanded bias (32768)
#define WQKV_O (BIAS_O + 32768)     // w_qkv bf16                    (196608)
#define BQKV_O (WQKV_O + 196608)    // b_qkv bf16                    (768)
#define WPRJ_O (BQKV_O + 768)       // w_proj bf16                   (65536)
#define BPRJ_O (WPRJ_O + 65536)     // b_proj bf16                   (256)

// ---- LDS: x tile [64][520B] = 33,280 B; reused as y tile after stage 1 ----
#define XROW 520
#define LDS_BYTES 33280

__device__ __forceinline__ float bf2f(u16 u) {
  union { u32 i; float f; } z; z.i = ((u32)u) << 16; return z.f;
}
__device__ __forceinline__ u16 f2bf(float f) {
  __bf16 h = (__bf16)f; return __builtin_bit_cast(u16, h);
}
__device__ __forceinline__ u32 pk2(float a, float b) {
  return (u32)f2bf(a) | ((u32)f2bf(b) << 16);
}
__device__ __forceinline__ float fetchf(const void* p, int idx, int isbf) {
  return isbf ? bf2f(((const u16*)p)[idx]) : ((const float*)p)[idx];
}

// Universal acc->frag repack (HW-verified rounds 6/7): converts an MFMA acc
// layout (rows via (g,reg) -> K-dim, cols via c -> lane-dim) into an operand frag.
__device__ __forceinline__ bf16x8 frag_from(u32 p00, u32 p01, u32 p10, u32 p11,
                                            int s0, int s1, bool hi) {
  u32 A0 = (u32)__shfl((int)p00, s0, 64);
  u32 A1 = (u32)__shfl((int)p01, s0, 64);
  u32 B0 = (u32)__shfl((int)p10, s0, 64);
  u32 B1 = (u32)__shfl((int)p11, s0, 64);
  u32 C0 = (u32)__shfl((int)p00, s1, 64);
  u32 C1 = (u32)__shfl((int)p01, s1, 64);
  u32 D0 = (u32)__shfl((int)p10, s1, 64);
  u32 D1 = (u32)__shfl((int)p11, s1, 64);
  u32x4 f;
  f[0] = hi ? B0 : A0;  f[1] = hi ? B1 : A1;
  f[2] = hi ? D0 : C0;  f[3] = hi ? D1 : C1;
  return __builtin_bit_cast(bf16x8, f);
}

__global__ void detect_dtype(const u16* __restrict__ x, int* __restrict__ flag) {
  __shared__ int cnt;
  if (threadIdx.x == 0) cnt = 0;
  __syncthreads();
  int sane = 0;
  for (int i = threadIdx.x; i < 2048; i += 256) {
    u16 u = x[2 * i];
    int e = (u >> 7) & 0xFF;
    sane += (e == 0 || (e >= 90 && e <= 160)) ? 1 : 0;
  }
  atomicAdd(&cnt, sane);
  __syncthreads();
  if (threadIdx.x == 0) *flag = (cnt >= 1638) ? 1 : 0;
}

// bias expanded to [h][n][m]
__global__ void cvt_params(const void* __restrict__ wqkv, const void* __restrict__ bqkv,
                           const void* __restrict__ btab, const void* __restrict__ wprj,
                           const void* __restrict__ bprj, void* __restrict__ wsraw) {
  u16* ws = (u16*)wsraw;
  const int isbf = *(const int*)wsraw;
  int i = blockIdx.x * 256 + threadIdx.x;
  if (i < 32768) {
    int n = (i >> 6) & 63, m = i & 63, h = i >> 12;
    int r0 = (n >> 3) - (m >> 3) + 7, r1 = (n & 7) - (m & 7) + 7;
    ws[BIAS_O + i] = f2bf(fetchf(btab, (r0 * 15 + r1) * NH + h, isbf));
  } else if (i < 32768 + 196608) {
    int j = i - 32768;
    ws[WQKV_O + j] = f2bf(fetchf(wqkv, j, isbf));
  } else if (i < 32768 + 196608 + 768) {
    int j = i - (32768 + 196608);
    ws[BQKV_O + j] = f2bf(fetchf(bqkv, j, isbf));
  } else if (i < 32768 + 196608 + 768 + 65536) {
    int j = i - (32768 + 196608 + 768);
    ws[WPRJ_O + j] = f2bf(fetchf(wprj, j, isbf));
  } else if (i < 32768 + 196608 + 768 + 65536 + 256) {
    int j = i - (32768 + 196608 + 768 + 65536);
    ws[BPRJ_O + j] = f2bf(fetchf(bprj, j, isbf));
  }
}

// Transposed qkv ch-tile: acc rows = channels CHB+4g+reg, cols = tokens 16nt+c.
#define TILE_T(PK, CHT, CHB, SCL) {                                                   \
    bf16x8 wf[8];                                                                     \
    const u16* wrow = ws + WQKV_O + ((CHB) + c) * CDIM;                               \
    _Pragma("unroll")                                                                 \
    for (int ks = 0; ks < 8; ++ks) wf[ks] = *(const bf16x8*)(wrow + ks * 32 + g * 8); \
    f32x4 binit;                                                                      \
    { u32x2 bp = *(const u32x2*)(ws + BQKV_O + (CHB) + 4 * g);                        \
      binit[0] = bf2f((u16)(bp[0] & 0xffff)); binit[1] = bf2f((u16)(bp[0] >> 16));    \
      binit[2] = bf2f((u16)(bp[1] & 0xffff)); binit[3] = bf2f((u16)(bp[1] >> 16)); }  \
    _Pragma("unroll")                                                                 \
    for (int nt = 0; nt < 4; ++nt) {                                                  \
      f32x4 acc = binit;                                                              \
      _Pragma("unroll")                                                               \
      for (int ks = 0; ks < 8; ++ks) {                                                \
        bf16x8 xf = *(const bf16x8*)(lds + (16 * nt + c) * XROW + ks * 64 + g * 16);  \
        acc = __builtin_amdgcn_mfma_f32_16x16x32_bf16(wf[ks], xf, acc, 0, 0, 0);      \
      }                                                                               \
      PK[CHT][nt][0] = pk2(acc[0] * (SCL), acc[1] * (SCL));                           \
      PK[CHT][nt][1] = pk2(acc[2] * (SCL), acc[3] * (SCL));                           \
    } }

// Normal qkv ch-tile (v): acc rows = tokens 16nt+4g+reg, col = channel CHB+c.
#define TILE_N(PK, CHT, CHB) {                                                        \
    bf16x8 wf[8];                                                                     \
    const u16* wrow = ws + WQKV_O + ((CHB) + c) * CDIM;                               \
    _Pragma("unroll")                                                                 \
    for (int ks = 0; ks < 8; ++ks) wf[ks] = *(const bf16x8*)(wrow + ks * 32 + g * 8); \
    const float badd = bf2f(ws[BQKV_O + (CHB) + c]);                                  \
    _Pragma("unroll")                                                                 \
    for (int nt = 0; nt < 4; ++nt) {                                                  \
      f32x4 acc = {badd, badd, badd, badd};                                           \
      _Pragma("unroll")                                                               \
      for (int ks = 0; ks < 8; ++ks) {                                                \
        bf16x8 xf = *(const bf16x8*)(lds + (16 * nt + c) * XROW + ks * 64 + g * 16);  \
        acc = __builtin_amdgcn_mfma_f32_16x16x32_bf16(xf, wf[ks], acc, 0, 0, 0);      \
      }                                                                               \
      PK[CHT][nt][0] = pk2(acc[0], acc[1]);                                           \
      PK[CHT][nt][1] = pk2(acc[2], acc[3]);                                           \
    } }

// launch_bounds(512, 2): VGPR cap 256 -> spills structurally impossible at our
// ~120 peak. (512,4)'s 128 cap caused the round-6/7 scratch catastrophes.
// If actual VGPR_Count lands <=128, HW still runs 2 blocks/CU (LDS allows 4).
__global__ __launch_bounds__(512, 2)
void win_attn_fused(const void* __restrict__ xraw, const void* __restrict__ wsraw,
                    float* __restrict__ out)
{
  __shared__ __align__(16) unsigned char lds[LDS_BYTES];
  const u16* ws  = (const u16*)wsraw;
  const int isbf = *(const int*)wsraw;
  const int b    = blockIdx.x;
  const int tid  = threadIdx.x;
  const int w    = tid >> 6;     // wave id = head id
  const int lane = tid & 63;
  const int c    = lane & 15;
  const int g    = lane >> 4;
  const float scale = 0.1767766952966369f;  // 32^-0.5

  // ---- stage 0: x[b] (64x256) -> LDS bf16 [64][520B]
  if (isbf) {
    const u32x4* gx = (const u32x4*)((const u16*)xraw + (size_t)b * (NTOK * CDIM));
#pragma unroll
    for (int i = 0; i < 4; ++i) {
      int q = tid + i * 512;
      int row = q >> 5, c8 = q & 31;
      *(u32x4*)(lds + row * XROW + c8 * 16) = gx[q];
    }
  } else {
    const f32x4* gx = (const f32x4*)((const float*)xraw + (size_t)b * (NTOK * CDIM));
#pragma unroll
    for (int i = 0; i < 8; ++i) {
      int q = tid + i * 512;
      int row = q >> 6, c4 = q & 63;
      f32x4 v = gx[q];
      u32x2 pkv;
      pkv[0] = pk2(v[0], v[1]);
      pkv[1] = pk2(v[2], v[3]);
      *(u32x2*)(lds + row * XROW + c4 * 8) = pkv;
    }
  }
  __syncthreads();   // B1

  const int s0 = c + 32 * (g & 1), s1 = s0 + 16;
  const bool hi = ((g >> 1) & 1) != 0;
  const int h = w;

  // ---- stage 1: per-head q,k (transposed) and v (normal), packed in registers
  u32 qpk[2][4][2], kpk[2][4][2];
  bf16x8 bvf[2][2];
  TILE_T(qpk, 0, 32 * w,            scale);
  TILE_T(qpk, 1, 32 * w + 16,       scale);
  TILE_T(kpk, 0, 256 + 32 * w,      1.0f);
  TILE_T(kpk, 1, 256 + 32 * w + 16, 1.0f);
  {
    u32 vpk[2][4][2];
    TILE_N(vpk, 0, 512 + 32 * w);
    TILE_N(vpk, 1, 512 + 32 * w + 16);
    // convert v -> B-frags NOW (frees vpk before the S^T/softmax phase)
#pragma unroll
    for (int dt = 0; dt < 2; ++dt)
#pragma unroll
      for (int k2 = 0; k2 < 2; ++k2)
        bvf[dt][k2] = frag_from(vpk[dt][2 * k2][0], vpk[dt][2 * k2][1],
                                vpk[dt][2 * k2 + 1][0], vpk[dt][2 * k2 + 1][1], s0, s1, hi);
  }
  __syncthreads();   // B2: x-LDS dead; region will hold y later

  // ---- S^T = k q^T + bias^T, softmax over m, P packed in regs (per-nt strips)
  bf16x8 bkf[4];
#pragma unroll
  for (int mt = 0; mt < 4; ++mt)
    bkf[mt] = frag_from(kpk[0][mt][0], kpk[0][mt][1], kpk[1][mt][0], kpk[1][mt][1], s0, s1, hi);

  u32 Ppk[4][4][2];
#pragma unroll
  for (int nt = 0; nt < 4; ++nt) {
    bf16x8 aqf = frag_from(qpk[0][nt][0], qpk[0][nt][1], qpk[1][nt][0], qpk[1][nt][1], s0, s1, hi);
    f32x4 st[4];
#pragma unroll
    for (int mt = 0; mt < 4; ++mt) {
      u32x2 bp = *(const u32x2*)(ws + BIAS_O + (h << 12) + ((16 * nt + c) << 6) + 16 * mt + 4 * g);
      st[mt][0] = bf2f((u16)(bp[0] & 0xffff)); st[mt][1] = bf2f((u16)(bp[0] >> 16));
      st[mt][2] = bf2f((u16)(bp[1] & 0xffff)); st[mt][3] = bf2f((u16)(bp[1] >> 16));
    }
#pragma unroll
    for (int mt = 0; mt < 4; ++mt)
      st[mt] = __builtin_amdgcn_mfma_f32_16x16x32_bf16(bkf[mt], aqf, st[mt], 0, 0, 0);
    float mx = st[0][0];
#pragma unroll
    for (int mt = 0; mt < 4; ++mt)
#pragma unroll
      for (int r = 0; r < 4; ++r) mx = fmaxf(mx, st[mt][r]);
    mx = fmaxf(mx, __shfl_xor(mx, 16));
    mx = fmaxf(mx, __shfl_xor(mx, 32));
    float sum = 0.f;
#pragma unroll
    for (int mt = 0; mt < 4; ++mt)
#pragma unroll
      for (int r = 0; r < 4; ++r) { float e = __expf(st[mt][r] - mx); st[mt][r] = e; sum += e; }
    sum += __shfl_xor(sum, 16);
    sum += __shfl_xor(sum, 32);
    float inv = 1.0f / sum;
#pragma unroll
    for (int mt = 0; mt < 4; ++mt) {
      Ppk[mt][nt][0] = pk2(st[mt][0] * inv, st[mt][1] * inv);
      Ppk[mt][nt][1] = pk2(st[mt][2] * inv, st[mt][3] * inv);
    }
  }

  // ---- PV in registers; paf built per-k2 (16 VGPR transient, not 32 resident)
  f32x4 o[4][2] = {{{0,0,0,0},{0,0,0,0}},{{0,0,0,0},{0,0,0,0}},
                   {{0,0,0,0},{0,0,0,0}},{{0,0,0,0},{0,0,0,0}}};
#pragma unroll
  for (int k2 = 0; k2 < 2; ++k2) {
    bf16x8 paf4[4];
#pragma unroll
    for (int nt = 0; nt < 4; ++nt)
      paf4[nt] = frag_from(Ppk[2 * k2][nt][0], Ppk[2 * k2][nt][1],
                           Ppk[2 * k2 + 1][nt][0], Ppk[2 * k2 + 1][nt][1], s0, s1, hi);
#pragma unroll
    for (int nt = 0; nt < 4; ++nt) {
      o[nt][0] = __builtin_amdgcn_mfma_f32_16x16x32_bf16(paf4[nt], bvf[0][k2], o[nt][0], 0, 0, 0);
      o[nt][1] = __builtin_amdgcn_mfma_f32_16x16x32_bf16(paf4[nt], bvf[1][k2], o[nt][1], 0, 0, 0);
    }
  }

  // ---- y[token][32w+16dt+c] -> LDS (region freed at B2; disjoint per-wave cols)
#pragma unroll
  for (int nt = 0; nt < 4; ++nt)
#pragma unroll
    for (int dt = 0; dt < 2; ++dt)
#pragma unroll
      for (int r = 0; r < 4; ++r) {
        int n = 16 * nt + 4 * g + r, col = 32 * w + 16 * dt + c;
        *(u16*)(lds + n * XROW + col * 2) = f2bf(o[nt][dt][r]);
      }
  __syncthreads();   // B3: y complete

  // ---- proj: out = y @ w_proj^T + b_proj ; direct f32 scatter (64B segments)
  float* gout = out + (size_t)b * (NTOK * CDIM);
#pragma unroll
  for (int ct = 0; ct < 2; ++ct) {
    const int colw = 32 * w + 16 * ct + c;
    const float badd = bf2f(ws[BPRJ_O + colw]);
    f32x4 acc[4];
#pragma unroll
    for (int rt = 0; rt < 4; ++rt)
#pragma unroll
      for (int r = 0; r < 4; ++r) acc[rt][r] = badd;
    const u16* wrow = ws + WPRJ_O + colw * CDIM;
#pragma unroll
    for (int ks = 0; ks < 8; ++ks) {
      bf16x8 wf = *(const bf16x8*)(wrow + ks * 32 + g * 8);
#pragma unroll
      for (int rt = 0; rt < 4; ++rt) {
        bf16x8 ay = *(const bf16x8*)(lds + (16 * rt + c) * XROW + ks * 64 + g * 16);
        acc[rt] = __builtin_amdgcn_mfma_f32_16x16x32_bf16(ay, wf, acc[rt], 0, 0, 0);
      }
    }
#pragma unroll
    for (int rt = 0; rt < 4; ++rt)
#pragma unroll
      for (int r = 0; r < 4; ++r) {
        int n = 16 * rt + 4 * g + r;
        gout[n * CDIM + colw] = acc[rt][r];
      }
  }
}

extern "C" void kernel_launch(void* const* d_in, const int* in_sizes, int n_in,
                              void* d_out, int out_size, void* d_ws, size_t ws_size,
                              hipStream_t stream) {
  (void)in_sizes; (void)n_in; (void)out_size; (void)ws_size;
  detect_dtype<<<dim3(1), dim3(256), 0, stream>>>((const u16*)d_in[0], (int*)d_ws);
  cvt_params<<<dim3(1156), dim3(256), 0, stream>>>(d_in[1], d_in[2], d_in[3], d_in[4],
                                                   d_in[5], d_ws);
  win_attn_fused<<<dim3(4096), dim3(512), 0, stream>>>(d_in[0], d_ws, (float*)d_out);
}